// Round 5
// baseline (759.769 us; speedup 1.0000x reference)
//
#include <hip/hip_runtime.h>
#include <math.h>

#define EPS 1e-5

constexpr int B = 32, C = 64, H = 128, W = 128;
constexpr int HW = H * W;                    // 16384 pairs per (b,c) plane
constexpr int NSAMP = B * HW;                // 524288 samples per channel
constexpr int PLANE_FLOATS = HW * 2;         // 32768 floats per plane
constexpr int PLANE_F4 = PLANE_FLOATS / 4;   // 8192 float4 per plane
constexpr int PLANES = B * C;                // 2048 blocks, one plane each
constexpr int NTHREADS = 256;                // 4 waves/block, 8 blocks/CU -> 32 waves/CU
constexpr int FLAG_STRIDE = 32;              // ints: one 128-B cache line per channel

typedef float vfloat4 __attribute__((ext_vector_type(4)));

// ws layout:
//   ws[0 .. 64*32)  ints : per-channel arrival counters, one cache line apart
//   ws[2048 + k*8 ..+4]  : block k's partial sums {S0,S1,S00,S01,S11}
__device__ __forceinline__ float agent_load_f32(const float* a) {
    unsigned int u = __hip_atomic_load((const unsigned int*)a,
                                       __ATOMIC_RELAXED, __HIP_MEMORY_SCOPE_AGENT);
    return __uint_as_float(u);
}

// Single kernel, 2048 blocks co-resident by exact capacity (proven round 4).
// Round-4 lesson: 19 polls/ns/line spin storm jammed the coherence fabric
// (hbm_gbps 2900->1212). Fix: per-channel flag lines + s_sleep(127) backoff
// (~3.4 us/poll) + last-arriver skips the spin.
__global__ __launch_bounds__(NTHREADS, 8) void fused_kernel(
    const float* __restrict__ z, float* __restrict__ ws,
    const float* __restrict__ gamma, const float* __restrict__ beta,
    float* __restrict__ out)
{
    const int k = blockIdx.x;            // plane index = b*C + c
    const int c = k & (C - 1);
    int* flags = (int*)ws;
    float* part = ws + C * FLAG_STRIDE;

    // ---- phase 1: reduce own plane, 4 independent load chains ----
    const vfloat4* p = (const vfloat4*)(z + (size_t)k * PLANE_FLOATS);
    float s0 = 0.f, s1 = 0.f, s00 = 0.f, s01 = 0.f, s11 = 0.f;
    for (int base = 0; base < PLANE_F4; base += 1024) {
        const int i = base + threadIdx.x;
        vfloat4 v0 = p[i];
        vfloat4 v1 = p[i + 256];
        vfloat4 v2 = p[i + 512];
        vfloat4 v3 = p[i + 768];
        s0  += (v0.x + v0.z) + (v1.x + v1.z) + (v2.x + v2.z) + (v3.x + v3.z);
        s1  += (v0.y + v0.w) + (v1.y + v1.w) + (v2.y + v2.w) + (v3.y + v3.w);
        s00 += (v0.x * v0.x + v0.z * v0.z) + (v1.x * v1.x + v1.z * v1.z)
             + (v2.x * v2.x + v2.z * v2.z) + (v3.x * v3.x + v3.z * v3.z);
        s11 += (v0.y * v0.y + v0.w * v0.w) + (v1.y * v1.y + v1.w * v1.w)
             + (v2.y * v2.y + v2.w * v2.w) + (v3.y * v3.y + v3.w * v3.w);
        s01 += (v0.x * v0.y + v0.z * v0.w) + (v1.x * v1.y + v1.z * v1.w)
             + (v2.x * v2.y + v2.z * v2.w) + (v3.x * v3.y + v3.z * v3.w);
    }

    #pragma unroll
    for (int o = 32; o > 0; o >>= 1) {
        s0  += __shfl_down(s0,  o, 64);
        s1  += __shfl_down(s1,  o, 64);
        s00 += __shfl_down(s00, o, 64);
        s01 += __shfl_down(s01, o, 64);
        s11 += __shfl_down(s11, o, 64);
    }

    __shared__ float sm[5][4];
    const int lane = threadIdx.x & 63;
    const int wv = threadIdx.x >> 6;
    if (lane == 0) {
        sm[0][wv] = s0; sm[1][wv] = s1; sm[2][wv] = s00; sm[3][wv] = s01; sm[4][wv] = s11;
    }
    __syncthreads();

    // ---- publish partial, low-pressure sync across the channel's 32 producers ----
    if (threadIdx.x == 0) {
        float t0 = 0.f, t1 = 0.f, t2 = 0.f, t3 = 0.f, t4 = 0.f;
        #pragma unroll
        for (int w = 0; w < 4; w++) {
            t0 += sm[0][w]; t1 += sm[1][w]; t2 += sm[2][w]; t3 += sm[3][w]; t4 += sm[4][w];
        }
        float* wp = part + (size_t)k * 8;
        wp[0] = t0; wp[1] = t1; wp[2] = t2; wp[3] = t3; wp[4] = t4;
        __threadfence();                              // release partials (device scope)
        const int my = __hip_atomic_fetch_add(&flags[c * FLAG_STRIDE], 1,
                                              __ATOMIC_ACQ_REL,
                                              __HIP_MEMORY_SCOPE_AGENT);
        if (my != B - 1) {
            // poll every ~3.4 us; acquire on each poll orders the partial reads
            while (__hip_atomic_load(&flags[c * FLAG_STRIDE], __ATOMIC_ACQUIRE,
                                     __HIP_MEMORY_SCOPE_AGENT) < B) {
                __builtin_amdgcn_s_sleep(127);
            }
        }
    }
    __syncthreads();   // block inherits thread 0's acquire-observation

    // ---- wave 0: sum the 32 per-plane partials, derive 2x2 affine ----
    __shared__ float tr[6];              // A00 A01 A10 A11 b0 b1
    if (threadIdx.x < 64) {
        float a0 = 0.f, a1 = 0.f, a2 = 0.f, a3 = 0.f, a4 = 0.f;
        if (threadIdx.x < B) {           // 32 partials per channel
            const float* pp = part + (size_t)(threadIdx.x * C + c) * 8;
            a0 = agent_load_f32(pp + 0);
            a1 = agent_load_f32(pp + 1);
            a2 = agent_load_f32(pp + 2);
            a3 = agent_load_f32(pp + 3);
            a4 = agent_load_f32(pp + 4);
        }
        #pragma unroll
        for (int o = 16; o > 0; o >>= 1) {
            a0 += __shfl_down(a0, o, 64);
            a1 += __shfl_down(a1, o, 64);
            a2 += __shfl_down(a2, o, 64);
            a3 += __shfl_down(a3, o, 64);
            a4 += __shfl_down(a4, o, 64);
        }
        if (threadIdx.x == 0) {
            const double S0 = a0, S1 = a1, S00 = a2, S01 = a3, S11 = a4;
            const double invN = 1.0 / (double)NSAMP;
            const double mu0 = S0 * invN, mu1 = S1 * invN;
            const double va = S00 * invN - mu0 * mu0 + EPS;
            const double vb = S01 * invN - mu0 * mu1;
            const double vd = S11 * invN - mu1 * mu1 + EPS;
            const double sdet = sqrt(va * vd - vb * vb);
            const double tt = sqrt(va + vd + 2.0 * sdet);
            const double sa = (va + sdet) / tt;
            const double sb = vb / tt;
            const double sd2 = (vd + sdet) / tt;
            const double inv_det = 1.0 / (sa * sd2 - sb * sb);
            const double w00 =  sd2 * inv_det;
            const double w01 = -sb  * inv_det;   // == w10 (symmetric)
            const double w11 =  sa  * inv_det;
            const double g00 = gamma[0], g01 = gamma[1], g10 = gamma[2], g11 = gamma[3];
            const double A00 = g00 * w00 + g01 * w01;
            const double A01 = g00 * w01 + g01 * w11;
            const double A10 = g10 * w00 + g11 * w01;
            const double A11 = g10 * w01 + g11 * w11;
            tr[0] = (float)A00; tr[1] = (float)A01; tr[2] = (float)A10; tr[3] = (float)A11;
            tr[4] = (float)((double)beta[0] - (A00 * mu0 + A01 * mu1));
            tr[5] = (float)((double)beta[1] - (A10 * mu0 + A11 * mu1));
        }
    }
    __syncthreads();
    const float A00 = tr[0], A01 = tr[1], A10 = tr[2], A11 = tr[3];
    const float b0 = tr[4], b1 = tr[5];

    // ---- phase 2: apply to own plane, reverse order (cache-warm tail first) ----
    vfloat4* qo = (vfloat4*)(out + (size_t)k * PLANE_FLOATS);
    for (int base = PLANE_F4 - 1024; base >= 0; base -= 1024) {
        const int i = base + threadIdx.x;
        vfloat4 v0 = p[i];
        vfloat4 v1 = p[i + 256];
        vfloat4 v2 = p[i + 512];
        vfloat4 v3 = p[i + 768];
        vfloat4 r0, r1, r2, r3;
        r0.x = A00 * v0.x + A01 * v0.y + b0;  r0.y = A10 * v0.x + A11 * v0.y + b1;
        r0.z = A00 * v0.z + A01 * v0.w + b0;  r0.w = A10 * v0.z + A11 * v0.w + b1;
        r1.x = A00 * v1.x + A01 * v1.y + b0;  r1.y = A10 * v1.x + A11 * v1.y + b1;
        r1.z = A00 * v1.z + A01 * v1.w + b0;  r1.w = A10 * v1.z + A11 * v1.w + b1;
        r2.x = A00 * v2.x + A01 * v2.y + b0;  r2.y = A10 * v2.x + A11 * v2.y + b1;
        r2.z = A00 * v2.z + A01 * v2.w + b0;  r2.w = A10 * v2.z + A11 * v2.w + b1;
        r3.x = A00 * v3.x + A01 * v3.y + b0;  r3.y = A10 * v3.x + A11 * v3.y + b1;
        r3.z = A00 * v3.z + A01 * v3.w + b0;  r3.w = A10 * v3.z + A11 * v3.w + b1;
        __builtin_nontemporal_store(r0, &qo[i]);
        __builtin_nontemporal_store(r1, &qo[i + 256]);
        __builtin_nontemporal_store(r2, &qo[i + 512]);
        __builtin_nontemporal_store(r3, &qo[i + 768]);
    }
}

extern "C" void kernel_launch(void* const* d_in, const int* in_sizes, int n_in,
                              void* d_out, int out_size, void* d_ws, size_t ws_size,
                              hipStream_t stream) {
    (void)in_sizes; (void)n_in; (void)out_size; (void)ws_size;
    const float* z     = (const float*)d_in[0];
    const float* gamma = (const float*)d_in[1];
    const float* beta  = (const float*)d_in[2];
    float* out = (float*)d_out;
    float* ws  = (float*)d_ws;

    // zero the 64 per-channel flag lines (8 KiB)
    (void)hipMemsetAsync(ws, 0, C * FLAG_STRIDE * sizeof(int), stream);
    fused_kernel<<<PLANES, NTHREADS, 0, stream>>>(z, ws, gamma, beta, out);
}

// Round 6
// 699.723 us; speedup vs baseline: 1.0858x; 1.0858x over previous
//
#include <hip/hip_runtime.h>
#include <math.h>

#define EPS 1e-5

constexpr int B = 32, C = 64, H = 128, W = 128;
constexpr int HW = H * W;                    // 16384 pairs per (b,c) plane
constexpr int NSAMP = B * HW;                // 524288 samples per channel
constexpr int PLANE_FLOATS = HW * 2;         // 32768 floats per plane
constexpr int PLANE_F4 = PLANE_FLOATS / 4;   // 8192 float4 per plane
constexpr int CHUNK_F4 = 1024;               // 16 KiB chunk = 1024 float4
constexpr int CHUNKS_PER_PLANE = PLANE_F4 / CHUNK_F4;   // 8
constexpr int CHUNKS_PER_CH = B * CHUNKS_PER_PLANE;     // 256 chunks per channel
constexpr int BLOCKS_PER_CH = 30;            // 30 producers per channel
constexpr int GRID = C * BLOCKS_PER_CH;      // 1920 blocks < 2048 capacity (slack!)
constexpr int NTHREADS = 256;                // 4 waves/block
constexpr int FLAG_STRIDE = 32;              // one 128-B line per channel

typedef float vfloat4 __attribute__((ext_vector_type(4)));

// ws layout (floats):
//   [0      .. 2048)  : int flags[ch*32]   — per-channel arrival counters
//   [2048   .. 4096)  : float acc[ch*32+j] — per-channel sums {S0,S1,S00,S01,S11}
// memset 16 KiB total.
__device__ __forceinline__ float agent_load_f32(const float* a) {
    unsigned int u = __hip_atomic_load((const unsigned int*)a,
                                       __ATOMIC_RELAXED, __HIP_MEMORY_SCOPE_AGENT);
    return __uint_as_float(u);
}

// Residency-imbalance-proof fused kernel (R4/R5 lesson: exact-capacity grids
// + inter-block barrier serialize into rounds; slack grid + fine chunks fix it).
// Each block: one channel, 8-9 strided 16-KiB chunks.
//   phase 1: reduce own chunks in registers -> 5 atomicAdds -> arrival counter
//   spin: channel counter < 30 (pattern validated R3; rate irrelevant per R5)
//   phase 2: transform once, re-apply to OWN chunks in reverse (cache-warm).
__global__ __launch_bounds__(NTHREADS) void fused_kernel(
    const float* __restrict__ z, float* __restrict__ ws,
    const float* __restrict__ gamma, const float* __restrict__ beta,
    float* __restrict__ out)
{
    const int blk = blockIdx.x;
    const int ch = blk / BLOCKS_PER_CH;
    const int r  = blk - ch * BLOCKS_PER_CH;     // 0..29
    int* flags = (int*)ws;
    float* acc = ws + 2048;

    const vfloat4* zf4 = (const vfloat4*)z;
    vfloat4* of4 = (vfloat4*)out;

    // ---- phase 1: reduce own chunks (all same channel) ----
    float s0 = 0.f, s1 = 0.f, s00 = 0.f, s01 = 0.f, s11 = 0.f;
    for (int c = r; c < CHUNKS_PER_CH; c += BLOCKS_PER_CH) {
        const int plane = (c >> 3) * C + ch;                 // b*C + ch
        const size_t base = (size_t)plane * PLANE_F4 + (size_t)(c & 7) * CHUNK_F4;
        const vfloat4* p = zf4 + base;
        vfloat4 v0 = p[threadIdx.x];
        vfloat4 v1 = p[threadIdx.x + 256];
        vfloat4 v2 = p[threadIdx.x + 512];
        vfloat4 v3 = p[threadIdx.x + 768];
        s0  += (v0.x + v0.z) + (v1.x + v1.z) + (v2.x + v2.z) + (v3.x + v3.z);
        s1  += (v0.y + v0.w) + (v1.y + v1.w) + (v2.y + v2.w) + (v3.y + v3.w);
        s00 += (v0.x * v0.x + v0.z * v0.z) + (v1.x * v1.x + v1.z * v1.z)
             + (v2.x * v2.x + v2.z * v2.z) + (v3.x * v3.x + v3.z * v3.z);
        s11 += (v0.y * v0.y + v0.w * v0.w) + (v1.y * v1.y + v1.w * v1.w)
             + (v2.y * v2.y + v2.w * v2.w) + (v3.y * v3.y + v3.w * v3.w);
        s01 += (v0.x * v0.y + v0.z * v0.w) + (v1.x * v1.y + v1.z * v1.w)
             + (v2.x * v2.y + v2.z * v2.w) + (v3.x * v3.y + v3.z * v3.w);
    }

    #pragma unroll
    for (int o = 32; o > 0; o >>= 1) {
        s0  += __shfl_down(s0,  o, 64);
        s1  += __shfl_down(s1,  o, 64);
        s00 += __shfl_down(s00, o, 64);
        s01 += __shfl_down(s01, o, 64);
        s11 += __shfl_down(s11, o, 64);
    }

    __shared__ float sm[5][4];
    const int lane = threadIdx.x & 63;
    const int wv = threadIdx.x >> 6;
    if (lane == 0) {
        sm[0][wv] = s0; sm[1][wv] = s1; sm[2][wv] = s00; sm[3][wv] = s01; sm[4][wv] = s11;
    }
    __syncthreads();

    // ---- publish into channel accumulator, arrive, spin to 30 ----
    if (threadIdx.x == 0) {
        float t0 = 0.f, t1 = 0.f, t2 = 0.f, t3 = 0.f, t4 = 0.f;
        #pragma unroll
        for (int w = 0; w < 4; w++) {
            t0 += sm[0][w]; t1 += sm[1][w]; t2 += sm[2][w]; t3 += sm[3][w]; t4 += sm[4][w];
        }
        float* ap = acc + ch * FLAG_STRIDE;
        atomicAdd(ap + 0, t0);
        atomicAdd(ap + 1, t1);
        atomicAdd(ap + 2, t2);
        atomicAdd(ap + 3, t3);
        atomicAdd(ap + 4, t4);
        __threadfence();                         // adds happen-before arrival
        __hip_atomic_fetch_add(&flags[ch * FLAG_STRIDE], 1,
                               __ATOMIC_ACQ_REL, __HIP_MEMORY_SCOPE_AGENT);
        while (__hip_atomic_load(&flags[ch * FLAG_STRIDE], __ATOMIC_ACQUIRE,
                                 __HIP_MEMORY_SCOPE_AGENT) < BLOCKS_PER_CH) {
            __builtin_amdgcn_s_sleep(32);
        }
    }
    __syncthreads();   // block inherits thread 0's acquire-observation

    // ---- transform (thread 0, double), broadcast via LDS ----
    __shared__ float tr[6];              // A00 A01 A10 A11 b0 b1
    if (threadIdx.x == 0) {
        const float* ap = acc + ch * FLAG_STRIDE;
        const double S0  = agent_load_f32(ap + 0);
        const double S1  = agent_load_f32(ap + 1);
        const double S00 = agent_load_f32(ap + 2);
        const double S01 = agent_load_f32(ap + 3);
        const double S11 = agent_load_f32(ap + 4);
        const double invN = 1.0 / (double)NSAMP;
        const double mu0 = S0 * invN, mu1 = S1 * invN;
        const double va = S00 * invN - mu0 * mu0 + EPS;
        const double vb = S01 * invN - mu0 * mu1;
        const double vd = S11 * invN - mu1 * mu1 + EPS;
        const double sdet = sqrt(va * vd - vb * vb);
        const double tt = sqrt(va + vd + 2.0 * sdet);
        const double sa = (va + sdet) / tt;
        const double sb = vb / tt;
        const double sd2 = (vd + sdet) / tt;
        const double inv_det = 1.0 / (sa * sd2 - sb * sb);
        const double w00 =  sd2 * inv_det;
        const double w01 = -sb  * inv_det;   // == w10 (symmetric)
        const double w11 =  sa  * inv_det;
        const double g00 = gamma[0], g01 = gamma[1], g10 = gamma[2], g11 = gamma[3];
        const double A00 = g00 * w00 + g01 * w01;
        const double A01 = g00 * w01 + g01 * w11;
        const double A10 = g10 * w00 + g11 * w01;
        const double A11 = g10 * w01 + g11 * w11;
        tr[0] = (float)A00; tr[1] = (float)A01; tr[2] = (float)A10; tr[3] = (float)A11;
        tr[4] = (float)((double)beta[0] - (A00 * mu0 + A01 * mu1));
        tr[5] = (float)((double)beta[1] - (A10 * mu0 + A11 * mu1));
    }
    __syncthreads();
    const float A00 = tr[0], A01 = tr[1], A10 = tr[2], A11 = tr[3];
    const float b0 = tr[4], b1 = tr[5];

    // ---- phase 2: apply to OWN chunks, reverse order (cache-warm first) ----
    const int nchunks = (CHUNKS_PER_CH - 1 - r) / BLOCKS_PER_CH + 1;   // 8 or 9
    const int clast = r + (nchunks - 1) * BLOCKS_PER_CH;
    for (int c = clast; c >= r; c -= BLOCKS_PER_CH) {
        const int plane = (c >> 3) * C + ch;
        const size_t base = (size_t)plane * PLANE_F4 + (size_t)(c & 7) * CHUNK_F4;
        const vfloat4* p = zf4 + base;
        vfloat4* q = of4 + base;
        vfloat4 v0 = p[threadIdx.x];
        vfloat4 v1 = p[threadIdx.x + 256];
        vfloat4 v2 = p[threadIdx.x + 512];
        vfloat4 v3 = p[threadIdx.x + 768];
        vfloat4 r0, r1, r2, r3;
        r0.x = A00 * v0.x + A01 * v0.y + b0;  r0.y = A10 * v0.x + A11 * v0.y + b1;
        r0.z = A00 * v0.z + A01 * v0.w + b0;  r0.w = A10 * v0.z + A11 * v0.w + b1;
        r1.x = A00 * v1.x + A01 * v1.y + b0;  r1.y = A10 * v1.x + A11 * v1.y + b1;
        r1.z = A00 * v1.z + A01 * v1.w + b0;  r1.w = A10 * v1.z + A11 * v1.w + b1;
        r2.x = A00 * v2.x + A01 * v2.y + b0;  r2.y = A10 * v2.x + A11 * v2.y + b1;
        r2.z = A00 * v2.z + A01 * v2.w + b0;  r2.w = A10 * v2.z + A11 * v2.w + b1;
        r3.x = A00 * v3.x + A01 * v3.y + b0;  r3.y = A10 * v3.x + A11 * v3.y + b1;
        r3.z = A00 * v3.z + A01 * v3.w + b0;  r3.w = A10 * v3.z + A11 * v3.w + b1;
        __builtin_nontemporal_store(r0, &q[threadIdx.x]);
        __builtin_nontemporal_store(r1, &q[threadIdx.x + 256]);
        __builtin_nontemporal_store(r2, &q[threadIdx.x + 512]);
        __builtin_nontemporal_store(r3, &q[threadIdx.x + 768]);
    }
}

extern "C" void kernel_launch(void* const* d_in, const int* in_sizes, int n_in,
                              void* d_out, int out_size, void* d_ws, size_t ws_size,
                              hipStream_t stream) {
    (void)in_sizes; (void)n_in; (void)out_size; (void)ws_size;
    const float* z     = (const float*)d_in[0];
    const float* gamma = (const float*)d_in[1];
    const float* beta  = (const float*)d_in[2];
    float* out = (float*)d_out;
    float* ws  = (float*)d_ws;

    // zero flags (8 KiB) + accumulators (8 KiB)
    (void)hipMemsetAsync(ws, 0, 4096 * sizeof(float), stream);
    fused_kernel<<<GRID, NTHREADS, 0, stream>>>(z, ws, gamma, beta, out);
}

// Round 7
// 522.312 us; speedup vs baseline: 1.4546x; 1.3397x over previous
//
#include <hip/hip_runtime.h>
#include <math.h>

#define EPS 1e-5

constexpr int B = 32, C = 64, H = 128, W = 128;
constexpr int HW = H * W;                    // 16384 pairs per (b,c) plane
constexpr int NSAMP = B * HW;                // 524288 samples per channel
constexpr int PLANE_FLOATS = HW * 2;         // 32768 floats per plane
constexpr int PLANE_F4 = PLANE_FLOATS / 4;   // 8192 float4 per plane
constexpr int SUBS = 8;                      // producer blocks per channel
constexpr int PLANES_PER_BLK = B / SUBS;     // 4 planes (512 KiB) per block
constexpr int GRID = C * SUBS;               // 512 blocks = 2 blocks/CU
constexpr int NTHREADS = 1024;               // 16 waves/block -> 32 waves/CU
constexpr int FLAG_STRIDE = 32;              // one 128-B line per channel

typedef float vfloat4 __attribute__((ext_vector_type(4)));

// ws layout (floats):
//   [0    .. 2048) : int flags[ch*32] — per-channel arrival counters (memset 8 KiB)
//   [2048 .. 6144) : float part[k*8 + j] — block k's partials {S0,S1,S00,S01,S11}
__device__ __forceinline__ float agent_load_f32(const float* a) {
    unsigned int u = __hip_atomic_load((const unsigned int*)a,
                                       __ATOMIC_RELAXED, __HIP_MEMORY_SCOPE_AGENT);
    return __uint_as_float(u);
}

// R3 structure (proven non-pathological: 1024-thr blocks, few spinners, fused
// barrier) at 2x the occupancy (512 blocks = 2/CU = 32 waves/CU). Isolates the
// "R3 was occupancy-limited" hypothesis. Block k: channel k&63, planes
// [sub*4, sub*4+4). Phase 2 re-applies to the SAME planes in reverse (block-
// local cache hits, proven R3/R4/R6: FETCH == one z read).
__global__ __launch_bounds__(NTHREADS, 8) void fused_kernel(
    const float* __restrict__ z, float* __restrict__ ws,
    const float* __restrict__ gamma, const float* __restrict__ beta,
    float* __restrict__ out)
{
    const int k = blockIdx.x;
    const int ch = k & (C - 1);
    const int sub = k >> 6;                  // 0..7
    int* flags = (int*)ws;
    float* part = ws + 2048;

    const vfloat4* zf4 = (const vfloat4*)z;
    vfloat4* of4 = (vfloat4*)out;

    // ---- phase 1: reduce own 4 planes, 4 independent load chains ----
    float s0 = 0.f, s1 = 0.f, s00 = 0.f, s01 = 0.f, s11 = 0.f;
    for (int j = 0; j < PLANES_PER_BLK; ++j) {
        const int plane = (sub * PLANES_PER_BLK + j) * C + ch;   // b*C + ch
        const vfloat4* p = zf4 + (size_t)plane * PLANE_F4;
        #pragma unroll
        for (int base = 0; base < PLANE_F4; base += 4096) {
            const int i = base + threadIdx.x;
            vfloat4 v0 = p[i];
            vfloat4 v1 = p[i + 1024];
            vfloat4 v2 = p[i + 2048];
            vfloat4 v3 = p[i + 3072];
            s0  += (v0.x + v0.z) + (v1.x + v1.z) + (v2.x + v2.z) + (v3.x + v3.z);
            s1  += (v0.y + v0.w) + (v1.y + v1.w) + (v2.y + v2.w) + (v3.y + v3.w);
            s00 += (v0.x * v0.x + v0.z * v0.z) + (v1.x * v1.x + v1.z * v1.z)
                 + (v2.x * v2.x + v2.z * v2.z) + (v3.x * v3.x + v3.z * v3.z);
            s11 += (v0.y * v0.y + v0.w * v0.w) + (v1.y * v1.y + v1.w * v1.w)
                 + (v2.y * v2.y + v2.w * v2.w) + (v3.y * v3.y + v3.w * v3.w);
            s01 += (v0.x * v0.y + v0.z * v0.w) + (v1.x * v1.y + v1.z * v1.w)
                 + (v2.x * v2.y + v2.z * v2.w) + (v3.x * v3.y + v3.z * v3.w);
        }
    }

    #pragma unroll
    for (int o = 32; o > 0; o >>= 1) {
        s0  += __shfl_down(s0,  o, 64);
        s1  += __shfl_down(s1,  o, 64);
        s00 += __shfl_down(s00, o, 64);
        s01 += __shfl_down(s01, o, 64);
        s11 += __shfl_down(s11, o, 64);
    }

    __shared__ float sm[5][16];
    const int lane = threadIdx.x & 63;
    const int wv = threadIdx.x >> 6;
    if (lane == 0) {
        sm[0][wv] = s0; sm[1][wv] = s1; sm[2][wv] = s00; sm[3][wv] = s01; sm[4][wv] = s11;
    }
    __syncthreads();

    // ---- publish partial, arrive, spin to 8 (rate proven irrelevant R5) ----
    if (threadIdx.x == 0) {
        float t0 = 0.f, t1 = 0.f, t2 = 0.f, t3 = 0.f, t4 = 0.f;
        #pragma unroll
        for (int w = 0; w < 16; w++) {
            t0 += sm[0][w]; t1 += sm[1][w]; t2 += sm[2][w]; t3 += sm[3][w]; t4 += sm[4][w];
        }
        float* wp = part + (size_t)k * 8;
        wp[0] = t0; wp[1] = t1; wp[2] = t2; wp[3] = t3; wp[4] = t4;
        __threadfence();                     // release partials (device scope)
        const int my = __hip_atomic_fetch_add(&flags[ch * FLAG_STRIDE], 1,
                                              __ATOMIC_ACQ_REL,
                                              __HIP_MEMORY_SCOPE_AGENT);
        if (my != SUBS - 1) {
            while (__hip_atomic_load(&flags[ch * FLAG_STRIDE], __ATOMIC_ACQUIRE,
                                     __HIP_MEMORY_SCOPE_AGENT) < SUBS) {
                __builtin_amdgcn_s_sleep(16);
            }
        }
    }
    __syncthreads();   // block inherits thread 0's acquire-observation

    // ---- wave 0: sum the channel's 8 partials, derive 2x2 affine ----
    __shared__ float tr[6];              // A00 A01 A10 A11 b0 b1
    if (threadIdx.x < 64) {
        float a0 = 0.f, a1 = 0.f, a2 = 0.f, a3 = 0.f, a4 = 0.f;
        if (threadIdx.x < SUBS) {        // 8 partials per channel
            const float* pp = part + (size_t)(threadIdx.x * C + ch) * 8;
            a0 = agent_load_f32(pp + 0);
            a1 = agent_load_f32(pp + 1);
            a2 = agent_load_f32(pp + 2);
            a3 = agent_load_f32(pp + 3);
            a4 = agent_load_f32(pp + 4);
        }
        #pragma unroll
        for (int o = 4; o > 0; o >>= 1) {
            a0 += __shfl_down(a0, o, 64);
            a1 += __shfl_down(a1, o, 64);
            a2 += __shfl_down(a2, o, 64);
            a3 += __shfl_down(a3, o, 64);
            a4 += __shfl_down(a4, o, 64);
        }
        if (threadIdx.x == 0) {
            const double S0 = a0, S1 = a1, S00 = a2, S01 = a3, S11 = a4;
            const double invN = 1.0 / (double)NSAMP;
            const double mu0 = S0 * invN, mu1 = S1 * invN;
            const double va = S00 * invN - mu0 * mu0 + EPS;
            const double vb = S01 * invN - mu0 * mu1;
            const double vd = S11 * invN - mu1 * mu1 + EPS;
            const double sdet = sqrt(va * vd - vb * vb);
            const double tt = sqrt(va + vd + 2.0 * sdet);
            const double sa = (va + sdet) / tt;
            const double sb = vb / tt;
            const double sd2 = (vd + sdet) / tt;
            const double inv_det = 1.0 / (sa * sd2 - sb * sb);
            const double w00 =  sd2 * inv_det;
            const double w01 = -sb  * inv_det;   // == w10 (symmetric)
            const double w11 =  sa  * inv_det;
            const double g00 = gamma[0], g01 = gamma[1], g10 = gamma[2], g11 = gamma[3];
            const double A00 = g00 * w00 + g01 * w01;
            const double A01 = g00 * w01 + g01 * w11;
            const double A10 = g10 * w00 + g11 * w01;
            const double A11 = g10 * w01 + g11 * w11;
            tr[0] = (float)A00; tr[1] = (float)A01; tr[2] = (float)A10; tr[3] = (float)A11;
            tr[4] = (float)((double)beta[0] - (A00 * mu0 + A01 * mu1));
            tr[5] = (float)((double)beta[1] - (A10 * mu0 + A11 * mu1));
        }
    }
    __syncthreads();
    const float A00 = tr[0], A01 = tr[1], A10 = tr[2], A11 = tr[3];
    const float b0 = tr[4], b1 = tr[5];

    // ---- phase 2: apply to OWN planes, reverse order (cache-warm first) ----
    for (int j = PLANES_PER_BLK - 1; j >= 0; --j) {
        const int plane = (sub * PLANES_PER_BLK + j) * C + ch;
        const size_t off = (size_t)plane * PLANE_F4;
        const vfloat4* p = zf4 + off;
        vfloat4* q = of4 + off;
        #pragma unroll
        for (int base = PLANE_F4 - 4096; base >= 0; base -= 4096) {
            const int i = base + threadIdx.x;
            vfloat4 v0 = p[i];
            vfloat4 v1 = p[i + 1024];
            vfloat4 v2 = p[i + 2048];
            vfloat4 v3 = p[i + 3072];
            vfloat4 r0, r1, r2, r3;
            r0.x = A00 * v0.x + A01 * v0.y + b0;  r0.y = A10 * v0.x + A11 * v0.y + b1;
            r0.z = A00 * v0.z + A01 * v0.w + b0;  r0.w = A10 * v0.z + A11 * v0.w + b1;
            r1.x = A00 * v1.x + A01 * v1.y + b0;  r1.y = A10 * v1.x + A11 * v1.y + b1;
            r1.z = A00 * v1.z + A01 * v1.w + b0;  r1.w = A10 * v1.z + A11 * v1.w + b1;
            r2.x = A00 * v2.x + A01 * v2.y + b0;  r2.y = A10 * v2.x + A11 * v2.y + b1;
            r2.z = A00 * v2.z + A01 * v2.w + b0;  r2.w = A10 * v2.z + A11 * v2.w + b1;
            r3.x = A00 * v3.x + A01 * v3.y + b0;  r3.y = A10 * v3.x + A11 * v3.y + b1;
            r3.z = A00 * v3.z + A01 * v3.w + b0;  r3.w = A10 * v3.z + A11 * v3.w + b1;
            __builtin_nontemporal_store(r0, &q[i]);
            __builtin_nontemporal_store(r1, &q[i + 1024]);
            __builtin_nontemporal_store(r2, &q[i + 2048]);
            __builtin_nontemporal_store(r3, &q[i + 3072]);
        }
    }
}

extern "C" void kernel_launch(void* const* d_in, const int* in_sizes, int n_in,
                              void* d_out, int out_size, void* d_ws, size_t ws_size,
                              hipStream_t stream) {
    (void)in_sizes; (void)n_in; (void)out_size; (void)ws_size;
    const float* z     = (const float*)d_in[0];
    const float* gamma = (const float*)d_in[1];
    const float* beta  = (const float*)d_in[2];
    float* out = (float*)d_out;
    float* ws  = (float*)d_ws;

    // zero the 64 per-channel flag lines (8 KiB)
    (void)hipMemsetAsync(ws, 0, C * FLAG_STRIDE * sizeof(int), stream);
    fused_kernel<<<GRID, NTHREADS, 0, stream>>>(z, ws, gamma, beta, out);
}